// Round 5
// baseline (244.348 us; speedup 1.0000x reference)
//
#include <hip/hip_runtime.h>

// ModulatedConv2d: B=16, IN=512, OUT=512, STYLE=512, K=3, H=W=32
// out[b,o] = scale[b,o] * conv2d(x[b,i]*s[b,i], W[o,i])   (shared weights!)
// Conv = one implicit GEMM: M=512 out-ch, N=16384 (b,px), K=9x512.
// x staged as zero-padded NHWC bf16 -> no boundary masking.
//
// R6: BK=32 global_load_lds 2-barrier loop: 107us, MfmaUtil 31%.
// R8: reg-staged pipeline (buffer_load->VGPR prefetch, ds_write dbuf LDS,
//     ONE barrier/step) + XOR swizzle: 96.6us, MfmaUtil 34%, 0 conflicts.
// R9: BK=64 w/ uint4 arrays in lambda -> SROA fail, scratch spill, 331us.
// R12: BK=64 scalarized: 91.6us, MfmaUtil 35%, WRITE 33MB (spill fixed).
//     Post-mortem: per-step cost is ~60% LDS TRAFFIC (16 ds_read_b128 +
//     8 ds_write_b128 per SIMD-step), not fixed barrier cost. BK
//     amortization exhausted.
// R13 (this): B OPERAND DIRECT FROM GLOBAL. B-frag layout (pixel row,
//     8 contiguous channels) == NHWC xpad layout, so the MFMA B operand
//     is a plain 16B global load: the whole B LDS round-trip was a copy.
//     Per step: 8 B-frag loads issued at top (in flight across A-commit +
//     barrier, L2-resident), A stays LDS-staged (2-wave reuse). ds_reads
//     halve 16->8, ds_writes halve 8->4, post-barrier chain is A-only.
//     + T5 setprio(1) around MFMA clusters. LDS 66->33KB.
//     Predict: conv ~70us, MfmaUtil ~47%, WRITE stays 33MB (no spill).

#define BATCH   16
#define CIN     512
#define COUT    512
#define IMG     32
#define PAD_IMG 34

static constexpr float AFF_SCALE = 0.044194173824159216f;  // 1/sqrt(512)
static constexpr float W_SCALE   = 0.014731391274719739f;  // 1/sqrt(512*9)

typedef __bf16 bf16x8 __attribute__((ext_vector_type(8)));
typedef float  f32x4  __attribute__((ext_vector_type(4)));

__device__ inline unsigned short f2bf(float f) {
    union { float f; unsigned int u; } v; v.f = f;
    unsigned int u = v.u;
    unsigned int r = (u + 0x7FFFu + ((u >> 16) & 1u)) >> 16;
    return (unsigned short)r;
}

__device__ inline float waveReduceSum(float v) {
    #pragma unroll
    for (int off = 32; off > 0; off >>= 1) v += __shfl_xor(v, off, 64);
    return v;
}

// ---- kernel 1: fused prep ----
__global__ void prep1(const float* __restrict__ cw,
                      const float* __restrict__ style,
                      const float* __restrict__ aw,
                      const float* __restrict__ ab,
                      unsigned short* __restrict__ w_t,
                      float* __restrict__ wsq,
                      float* __restrict__ s_out) {
    const int tid = threadIdx.x;
    if (blockIdx.x < 1024) {
        __shared__ float wl[2304];
        const float* src = cw + (size_t)blockIdx.x * 2304;
        for (int j = tid; j < 2304; j += 256) wl[j] = src[j];
        __syncthreads();
        const int idx = blockIdx.x * 256 + tid;       // o*512 + i
        const int base = tid * 9;
        float acc = 0.f;
        #pragma unroll
        for (int e = 0; e < 9; ++e) {
            float v = wl[base + e];
            acc += v * v;
            w_t[e * (COUT * CIN) + idx] = f2bf(v);
        }
        wsq[idx] = acc;
    } else {
        const int q = blockIdx.x - 1024;              // 0..2047
        const int b = q >> 7;
        const int i = (q & 127) * 4 + (tid >> 6);
        const int lane = tid & 63;
        float sum = 0.f;
        #pragma unroll
        for (int k = 0; k < 512; k += 64)
            sum += style[b * 512 + k + lane] * aw[i * 512 + k + lane];
        sum = waveReduceSum(sum);
        if (lane == 0)
            s_out[b * 512 + i] = sum * AFF_SCALE + ab[i] + 1.0f;
    }
}

// ---- kernel 2: fused xpad + scale ----
__global__ void prep2(const float* __restrict__ x,
                      const float* __restrict__ s_in,
                      const float* __restrict__ wsq,
                      unsigned short* __restrict__ xpad,
                      float* __restrict__ scl) {
    const int tid = threadIdx.x;
    if (blockIdx.x >= 4352) {
        const int q = blockIdx.x - 4352;              // 0..2047
        const int b = q >> 7;                         // 0..15
        const int o = (q & 127) * 4 + (tid >> 6);     // 0..511
        const int lane = tid & 63;
        float sum = 0.f;
        #pragma unroll
        for (int i = 0; i < 512; i += 64) {
            float sv = s_in[b * 512 + i + lane];
            sum += sv * sv * wsq[o * 512 + i + lane];
        }
        sum = waveReduceSum(sum);
        if (lane == 0)
            scl[b * 512 + o] = W_SCALE * rsqrtf(W_SCALE * W_SCALE * sum + 1e-8f);
        return;
    }
    const int c0   = blockIdx.x & 7;                  // *64 channels
    const int rest = blockIdx.x >> 3;                 // 0..543
    const int hh   = rest % 34;
    const int b    = rest / 34;
    const int c0b  = c0 * 64;
    unsigned short* rowbase = xpad + (((size_t)b * PAD_IMG + hh) * PAD_IMG) * 512;

    if (hh == 0 || hh == PAD_IMG - 1) {
        for (int j = tid; j < 34 * 32; j += 256) {
            int ww = j >> 5, cp = (j & 31) * 2;
            *(unsigned int*)(rowbase + (size_t)ww * 512 + c0b + cp) = 0u;
        }
        return;
    }

    __shared__ float t[64][33];
    const int h = hh - 1;
    {
        const int wx = tid & 31;
        const int cb = (tid >> 5) * 8;
        const float* xb = x + (((size_t)b * 512 + c0b + cb) * IMG + h) * IMG + wx;
        #pragma unroll
        for (int j = 0; j < 8; ++j)
            t[cb + j][wx] = xb[(size_t)j * (IMG * IMG)] * s_in[b * 512 + c0b + cb + j];
    }
    __syncthreads();
    {
        const int p  = tid >> 3;
        const int cc = (tid & 7) * 8;
        unsigned short* dst = rowbase + (size_t)(p + 1) * 512 + c0b + cc;
        uint4 pk;
        pk.x = (unsigned)f2bf(t[cc + 0][p]) | ((unsigned)f2bf(t[cc + 1][p]) << 16);
        pk.y = (unsigned)f2bf(t[cc + 2][p]) | ((unsigned)f2bf(t[cc + 3][p]) << 16);
        pk.z = (unsigned)f2bf(t[cc + 4][p]) | ((unsigned)f2bf(t[cc + 5][p]) << 16);
        pk.w = (unsigned)f2bf(t[cc + 6][p]) | ((unsigned)f2bf(t[cc + 7][p]) << 16);
        *(uint4*)dst = pk;
    }
    if (tid < 64) {
        int ww = (tid >> 5) ? (PAD_IMG - 1) : 0;
        int cp = (tid & 31) * 2;
        *(unsigned int*)(rowbase + (size_t)ww * 512 + c0b + cp) = 0u;
    }
}

// ---- kernel 3: implicit-GEMM conv, 128x128 tile, BK=64, bf16 MFMA ----
// A: LDS-staged (reg prefetch, dbuf, XOR swizzle). B: DIRECT from global
// (NHWC == frag layout). One barrier/step, 32 MFMA/wave/step.
// grid 512 (XCD-swizzled), block 256 (4 waves), 2 blocks/CU.

// A loader: step -> 4 named uint4 regs (128x64 slab)
#define LOADA(stp) do {                                                       \
    const int e_  = (stp) >> 3;                                               \
    const int kc_ = ((stp) & 7) << 6;                                         \
    const unsigned short* Ab_ = wt + (size_t)e_ * (COUT * CIN)                \
                                   + (size_t)m0 * 512 + kc_;                  \
    ra0 = *(const uint4*)(Ab_ + aOff0);                                       \
    ra1 = *(const uint4*)(Ab_ + aOff1);                                       \
    ra2 = *(const uint4*)(Ab_ + aOff2);                                       \
    ra3 = *(const uint4*)(Ab_ + aOff3);                                       \
} while (0)

// B loader: step -> 8 named uint4 frag regs (consumed by MFMA directly).
// pb0..3 = half-cluster k 0..31 (ni 0..3); pb4..7 = k 32..63.
#define LOADB(stp) do {                                                       \
    const int e_  = (stp) >> 3;                                               \
    const int kc_ = ((stp) & 7) << 6;                                         \
    const int kh_ = (e_ * 11) >> 5;                                           \
    const int kw_ = e_ - kh_ * 3;                                             \
    const unsigned short* Bb_ = xpad + bImgBase                               \
        + (size_t)((h0 + kh_) * PAD_IMG + kw_) * 512 + kc_;                   \
    pb0 = *(const uint4*)(Bb_ + pOff0);                                       \
    pb1 = *(const uint4*)(Bb_ + pOff1);                                       \
    pb2 = *(const uint4*)(Bb_ + pOff2);                                       \
    pb3 = *(const uint4*)(Bb_ + pOff3);                                       \
    pb4 = *(const uint4*)(Bb_ + pOff0 + 32);                                  \
    pb5 = *(const uint4*)(Bb_ + pOff1 + 32);                                  \
    pb6 = *(const uint4*)(Bb_ + pOff2 + 32);                                  \
    pb7 = *(const uint4*)(Bb_ + pOff3 + 32);                                  \
} while (0)

__global__ __launch_bounds__(256, 2) void conv_mfma(
    const unsigned short* __restrict__ wt,    // [9][512][512] bf16
    const unsigned short* __restrict__ xpad,  // [16][34][34][512] bf16
    const float* __restrict__ scl,            // [16][512]
    float* __restrict__ out)                  // [16][512][32][32]
{
    __shared__ __align__(16) unsigned short Alds[2][128 * 64];  // 2 x 16 KB
    __shared__ float sclds[128];

    const int tid = threadIdx.x;
    // XCD swizzle: id&7 -> XCD. Each XCD: 16 (h,b)-pairs x 4 m-blocks.
    const int id    = blockIdx.x;
    const int xcd   = id & 7;
    const int local = id >> 3;                   // 0..63
    const int gp    = xcd * 16 + (local >> 2);   // 0..127  (h,b) pair
    const int m0  = (local & 3) * 128;
    const int h0  = (gp & 7) * 4;
    const int b   = gp >> 3;

    if (tid < 128) sclds[tid] = scl[b * 512 + m0 + tid];

    const int wid  = tid >> 6;
    const int lane = tid & 63;
    const int wm = wid & 1, wn = wid >> 1;

    const f32x4 vzero = {0.f, 0.f, 0.f, 0.f};
    f32x4 acc[4][4];
    #pragma unroll
    for (int i = 0; i < 4; ++i)
        #pragma unroll
        for (int j = 0; j < 4; ++j) acc[i][j] = vzero;

    // A staging: thread f = r*256+tid owns (row=f>>3, chunk c=f&7) of the
    // 128x64 A tile. LDS slot XOR-swizzled: p = c ^ (row&7). All offsets
    // NAMED SCALARS (R9 lesson: arrays in the loader -> scratch spill).
    int aOff0, aOff1, aOff2, aOff3;
    int lOff0, lOff1, lOff2, lOff3;
    {
        int f, row, c, p;
        f = tid;             row = f >> 3; c = f & 7; p = c ^ (row & 7);
        aOff0 = row * 512 + c * 8;  lOff0 = row * 64 + p * 8;
        f = 256 + tid;       row = f >> 3; c = f & 7; p = c ^ (row & 7);
        aOff1 = row * 512 + c * 8;  lOff1 = row * 64 + p * 8;
        f = 512 + tid;       row = f >> 3; c = f & 7; p = c ^ (row & 7);
        aOff2 = row * 512 + c * 8;  lOff2 = row * 64 + p * 8;
        f = 768 + tid;       row = f >> 3; c = f & 7; p = c ^ (row & 7);
        aOff3 = row * 512 + c * 8;  lOff3 = row * 64 + p * 8;
    }

    const size_t bImgBase = (size_t)b * PAD_IMG * PAD_IMG * 512;

    // fragment geometry
    const int rl   = lane & 15;
    const int kch  = lane >> 4;                  // 0..3 (8-ch chunk within k32)
    // A LDS read swizzle: chunk (ks*4+kch) at position ^(row&7); wbase%16==0.
    const int sw   = rl & 7;
    const int swz0 = (kch ^ sw) * 8;             // k 0..31
    const int swz1 = ((kch + 4) ^ sw) * 8;       // k 32..63
    const int arow = (wm * 64 + rl) * 64;
    // B per-lane pixel offsets (shorts), constant per lane: frag ni reads
    // pixel prow = wn*64 + ni*16 + rl of the 128-px tile; img row = prow>>5,
    // col = prow&31; + channel chunk kch*8.
    int pOff0, pOff1, pOff2, pOff3;
    {
        int pr;
        pr = wn * 64 + 0 * 16 + rl;
        pOff0 = ((pr >> 5) * PAD_IMG + (pr & 31)) * 512 + kch * 8;
        pr = wn * 64 + 1 * 16 + rl;
        pOff1 = ((pr >> 5) * PAD_IMG + (pr & 31)) * 512 + kch * 8;
        pr = wn * 64 + 2 * 16 + rl;
        pOff2 = ((pr >> 5) * PAD_IMG + (pr & 31)) * 512 + kch * 8;
        pr = wn * 64 + 3 * 16 + rl;
        pOff3 = ((pr >> 5) * PAD_IMG + (pr & 31)) * 512 + kch * 8;
    }

    // prefetch state: named uint4 scalars (SROA-safe)
    uint4 ra0, ra1, ra2, ra3;                    // A slab (step+1)
    uint4 pb0, pb1, pb2, pb3, pb4, pb5, pb6, pb7; // B frags (this step)

    LOADA(0);

    for (int step = 0; step < 72; ++step) {
        const int buf = step & 1;
        // B frags for THIS step: in flight across A-commit + barrier
        // (~300cy) -> L2 latency hidden. No LDS round-trip for B.
        LOADB(step);
        // commit prefetched A regs to LDS (counted vmcnt waits only for
        // the A loads issued one iteration ago -- B loads above are newer)
        *(uint4*)(&Alds[buf][lOff0]) = ra0;
        *(uint4*)(&Alds[buf][lOff1]) = ra1;
        *(uint4*)(&Alds[buf][lOff2]) = ra2;
        *(uint4*)(&Alds[buf][lOff3]) = ra3;
        // issue next step's A loads; in flight across the barrier
        const int nxt = step + 1 < 72 ? step + 1 : 71;
        LOADA(nxt);
        __syncthreads();

        // half-cluster 1: k 0..31
        {
            bf16x8 af[4];
            #pragma unroll
            for (int mi = 0; mi < 4; ++mi)
                af[mi] = *(const bf16x8*)(&Alds[buf][arow + mi * (16 * 64) + swz0]);
            const bf16x8 b0 = __builtin_bit_cast(bf16x8, pb0);
            const bf16x8 b1 = __builtin_bit_cast(bf16x8, pb1);
            const bf16x8 b2 = __builtin_bit_cast(bf16x8, pb2);
            const bf16x8 b3 = __builtin_bit_cast(bf16x8, pb3);
            __builtin_amdgcn_s_setprio(1);
            #pragma unroll
            for (int mi = 0; mi < 4; ++mi) {
                acc[mi][0] = __builtin_amdgcn_mfma_f32_16x16x32_bf16(
                    af[mi], b0, acc[mi][0], 0, 0, 0);
                acc[mi][1] = __builtin_amdgcn_mfma_f32_16x16x32_bf16(
                    af[mi], b1, acc[mi][1], 0, 0, 0);
                acc[mi][2] = __builtin_amdgcn_mfma_f32_16x16x32_bf16(
                    af[mi], b2, acc[mi][2], 0, 0, 0);
                acc[mi][3] = __builtin_amdgcn_mfma_f32_16x16x32_bf16(
                    af[mi], b3, acc[mi][3], 0, 0, 0);
            }
            __builtin_amdgcn_s_setprio(0);
        }
        // half-cluster 2: k 32..63
        {
            bf16x8 af[4];
            #pragma unroll
            for (int mi = 0; mi < 4; ++mi)
                af[mi] = *(const bf16x8*)(&Alds[buf][arow + mi * (16 * 64) + swz1]);
            const bf16x8 b4 = __builtin_bit_cast(bf16x8, pb4);
            const bf16x8 b5 = __builtin_bit_cast(bf16x8, pb5);
            const bf16x8 b6 = __builtin_bit_cast(bf16x8, pb6);
            const bf16x8 b7 = __builtin_bit_cast(bf16x8, pb7);
            __builtin_amdgcn_s_setprio(1);
            #pragma unroll
            for (int mi = 0; mi < 4; ++mi) {
                acc[mi][0] = __builtin_amdgcn_mfma_f32_16x16x32_bf16(
                    af[mi], b4, acc[mi][0], 0, 0, 0);
                acc[mi][1] = __builtin_amdgcn_mfma_f32_16x16x32_bf16(
                    af[mi], b5, acc[mi][1], 0, 0, 0);
                acc[mi][2] = __builtin_amdgcn_mfma_f32_16x16x32_bf16(
                    af[mi], b6, acc[mi][2], 0, 0, 0);
                acc[mi][3] = __builtin_amdgcn_mfma_f32_16x16x32_bf16(
                    af[mi], b7, acc[mi][3], 0, 0, 0);
            }
            __builtin_amdgcn_s_setprio(0);
        }
        // single barrier/step: next iter's A ds_write targets buf^1, whose
        // last readers (step-1) finished before barrier(step).
    }

    // epilogue: C[m][n] layout col=lane&15, row=(lane>>4)*4+reg  [m89-verified]
    const int colp = lane & 15;
    const int rowq = (lane >> 4) * 4;
    const int p0 = h0 * 32;
    #pragma unroll
    for (int mi = 0; mi < 4; ++mi) {
        #pragma unroll
        for (int ni = 0; ni < 4; ++ni) {
            const int p = p0 + wn * 64 + ni * 16 + colp;
            #pragma unroll
            for (int r2 = 0; r2 < 4; ++r2) {
                const int ol = wm * 64 + mi * 16 + rowq + r2;
                out[(((size_t)b * 512 + m0 + ol) << 10) + p] =
                    acc[mi][ni][r2] * sclds[ol];
            }
        }
    }
}

extern "C" void kernel_launch(void* const* d_in, const int* in_sizes, int n_in,
                              void* d_out, int out_size, void* d_ws, size_t ws_size,
                              hipStream_t stream) {
    const float* x     = (const float*)d_in[0];  // [16,512,32,32]
    const float* style = (const float*)d_in[1];  // [16,512]
    const float* aw    = (const float*)d_in[2];  // [512,512]
    const float* ab    = (const float*)d_in[3];  // [512]
    const float* cw    = (const float*)d_in[4];  // [512,512,3,3]
    float* out = (float*)d_out;

    char* ws = (char*)d_ws;
    float* s_buf          = (float*)(ws);                      //  32 KB
    float* scl            = (float*)(ws + 32768);              //  32 KB
    float* wsq            = (float*)(ws + 65536);              //   1 MB
    unsigned short* w_t   = (unsigned short*)(ws + 1114112);   // 4.5 MB bf16
    unsigned short* x_pad = (unsigned short*)(ws + 5832704);   // 18.9 MB bf16
    // total ws need: 24,772,608 B

    prep1<<<dim3(3072), 256, 0, stream>>>(cw, style, aw, ab, w_t, wsq, s_buf);
    prep2<<<dim3(6400), 256, 0, stream>>>(x, s_buf, wsq, x_pad, scl);
    conv_mfma<<<dim3(512), 256, 0, stream>>>(w_t, x_pad, scl, out);
}